// Round 2
// baseline (250.651 us; speedup 1.0000x reference)
//
#include <hip/hip_runtime.h>

// Depthwise 5x5 box blur, zero 'same' padding, (16,8,512,512) fp32.
// Wave-streaming, LDS-free, barrier-free:
//   - each 64-lane wave owns a 16-output-row strip of one plane
//   - lane owns 8 contiguous columns (2x float4 load/store per row)
//   - horizontal 5-window halo via __shfl_up/__shfl_down (wave spans full 512-col row)
//   - vertical 5-window = ring buffer of 5 horizontal-sum rows in registers
// No __syncthreads -> loads stream continuously, hiding HBM latency.

#define H 512
#define W 512
#define RSTRIP 16   // output rows per wave; halo overhead 20/16 = 25% (L2/L3-absorbed)

__global__ __launch_bounds__(256, 4) void avefilter_kernel(
    const float* __restrict__ x, const float* __restrict__ wgt,
    float* __restrict__ out)
{
    const int lane  = threadIdx.x & 63;
    const int wave  = threadIdx.x >> 6;
    const int strip = blockIdx.x * 4 + wave;      // 0 .. 4095
    const int plane = strip >> 5;                 // 32 strips per plane
    const int r0    = (strip & 31) * RSTRIP;

    const float* in   = x   + (size_t)plane * (H * W);
    float*       outp = out + (size_t)plane * (H * W);
    const float scale = wgt[0];                   // uniform kernel: sum * w[0]

    const int c0 = lane * 8;                      // 8 contiguous cols per lane

    float hr[5][8];                               // ring of horizontal-sum rows

    // Load input row gr (zeros outside [0,H)), produce 8 horizontal 5-sums.
    auto make_h = [&](int gr, float h[8]) {
        float v[8];
        if (gr >= 0 && gr < H) {                  // wave-uniform branch
            const float4* p = (const float4*)(in + (size_t)gr * W + c0);
            float4 a = p[0], b = p[1];
            v[0]=a.x; v[1]=a.y; v[2]=a.z; v[3]=a.w;
            v[4]=b.x; v[5]=b.y; v[6]=b.z; v[7]=b.w;
        } else {
            #pragma unroll
            for (int j = 0; j < 8; ++j) v[j] = 0.f;
        }
        // halo: 2 px from each neighbor lane; lane 0 / lane 63 see zero padding
        float l6 = __shfl_up(v[6], 1);
        float l7 = __shfl_up(v[7], 1);
        float rA = __shfl_down(v[0], 1);
        float rB = __shfl_down(v[1], 1);
        if (lane == 0)  { l6 = 0.f; l7 = 0.f; }
        if (lane == 63) { rA = 0.f; rB = 0.f; }
        float e[12];
        e[0] = l6; e[1] = l7;
        #pragma unroll
        for (int j = 0; j < 8; ++j) e[2 + j] = v[j];
        e[10] = rA; e[11] = rB;
        #pragma unroll
        for (int j = 0; j < 8; ++j)
            h[j] = e[j] + e[j+1] + e[j+2] + e[j+3] + e[j+4];
    };

    // Prologue: h-rows for input rows r0-2 .. r0+1
    #pragma unroll
    for (int k = 0; k < 4; ++k)
        make_h(r0 - 2 + k, hr[k]);

    // Main: for each output row, bring in row r0+2+r, sum all 5 ring slots.
    #pragma unroll
    for (int r = 0; r < RSTRIP; ++r) {
        make_h(r0 + 2 + r, hr[(r + 4) % 5]);
        float o[8];
        #pragma unroll
        for (int j = 0; j < 8; ++j)
            o[j] = (hr[0][j] + hr[1][j] + hr[2][j] + hr[3][j] + hr[4][j]) * scale;
        float4* q = (float4*)(outp + (size_t)(r0 + r) * W + c0);
        q[0] = make_float4(o[0], o[1], o[2], o[3]);
        q[1] = make_float4(o[4], o[5], o[6], o[7]);
    }
}

extern "C" void kernel_launch(void* const* d_in, const int* in_sizes, int n_in,
                              void* d_out, int out_size, void* d_ws, size_t ws_size,
                              hipStream_t stream) {
    const float* x   = (const float*)d_in[0];
    const float* wgt = (const float*)d_in[1];
    float* out = (float*)d_out;

    // 128 planes * 32 strips = 4096 waves = 1024 blocks of 4 waves
    dim3 grid(1024);
    dim3 block(256);
    avefilter_kernel<<<grid, block, 0, stream>>>(x, wgt, out);
}

// Round 3
// 244.331 us; speedup vs baseline: 1.0259x; 1.0259x over previous
//
#include <hip/hip_runtime.h>

// Depthwise 5x5 box blur, zero 'same' padding, (16,8,512,512) fp32.
// Wave-streaming, LDS/barrier-free, occupancy-maximized:
//   - each 64-lane wave owns a 256-col half-row x 16-output-row strip
//   - lane owns 4 CONTIGUOUS cols -> every load/store instruction covers a
//     dense 1 KB (fixes R1's 28% write amplification from interleaved stores)
//   - horizontal halo: 4 shuffles + 8-B edge loads on the seam lanes
//   - vertical 5-window: ring of 5 h-sum rows in registers (20 VGPRs)
//   - launch_bounds(256,8) caps VGPR at 64 -> 32 waves/CU (100% occupancy);
//     BW tracked waves/CU in R0/R1 (12w->2.45, 16w->2.65 TB/s): latency-bound
//   - nontemporal stores: output never re-read, keep L2/L3 for input halos

#define H 512
#define W 512
#define RSTRIP 16

typedef float vfloat4 __attribute__((ext_vector_type(4)));

__global__ __launch_bounds__(256, 8) void avefilter_kernel(
    const float* __restrict__ x, const float* __restrict__ wgt,
    float* __restrict__ out)
{
    const int lane = threadIdx.x & 63;
    const int wv   = threadIdx.x >> 6;
    const int g    = blockIdx.x * 4 + wv;   // 0..8191 wave id
    const int plane = g >> 6;               // 64 waves per plane
    const int s     = g & 63;
    const int half  = s & 1;                // adjacent waves = adjacent halves
    const int strip = s >> 1;
    const int r0    = strip * RSTRIP;
    const int col0  = half * 256;

    const float* in   = x   + (size_t)plane * (H * W);
    float*       outp = out + (size_t)plane * (H * W);
    const float scale = wgt[0];             // uniform kernel: sum * w[0]

    const int c = col0 + lane * 4;          // 4 contiguous cols per lane

    float hr[5][4];                         // ring of horizontal-sum rows

    // Load half-row of input row gr (zeros outside [0,H)), make 4 h-sums.
    auto make_h = [&](int gr, float h[4]) {
        float4 v  = make_float4(0.f, 0.f, 0.f, 0.f);
        float2 lh = make_float2(0.f, 0.f);  // cols col0-2, col0-1 (lane 0)
        float2 rh = make_float2(0.f, 0.f);  // cols col0+256, +257 (lane 63)
        if (gr >= 0 && gr < H) {            // wave-uniform branch
            const float* rowp = in + (size_t)gr * W;
            v = *(const float4*)(rowp + c);
            if (lane == 0 && col0 > 0)
                lh = *(const float2*)(rowp + col0 - 2);
            if (lane == 63 && col0 + 256 < W)
                rh = *(const float2*)(rowp + col0 + 256);
        }
        float l2  = __shfl_up(v.z, 1);
        float l3  = __shfl_up(v.w, 1);
        float rr0 = __shfl_down(v.x, 1);
        float rr1 = __shfl_down(v.y, 1);
        if (lane == 0)  { l2 = lh.x;  l3 = lh.y; }
        if (lane == 63) { rr0 = rh.x; rr1 = rh.y; }
        h[0] = l2  + l3  + v.x + v.y + v.z;
        h[1] = l3  + v.x + v.y + v.z + v.w;
        h[2] = v.x + v.y + v.z + v.w + rr0;
        h[3] = v.y + v.z + v.w + rr0 + rr1;
    };

    // Prologue: input rows r0-2 .. r0+1
    #pragma unroll
    for (int k = 0; k < 4; ++k)
        make_h(r0 - 2 + k, hr[k]);

    // Slide: bring in row r0+2+r, sum 5 ring slots, store output row r0+r.
    #pragma unroll
    for (int r = 0; r < RSTRIP; ++r) {
        make_h(r0 + 2 + r, hr[(r + 4) % 5]);
        vfloat4 o;
        #pragma unroll
        for (int j = 0; j < 4; ++j)
            o[j] = (hr[0][j] + hr[1][j] + hr[2][j] + hr[3][j] + hr[4][j]) * scale;
        __builtin_nontemporal_store(o, (vfloat4*)(outp + (size_t)(r0 + r) * W + c));
    }
}

extern "C" void kernel_launch(void* const* d_in, const int* in_sizes, int n_in,
                              void* d_out, int out_size, void* d_ws, size_t ws_size,
                              hipStream_t stream) {
    const float* x   = (const float*)d_in[0];
    const float* wgt = (const float*)d_in[1];
    float* out = (float*)d_out;

    // 128 planes * 32 strips * 2 halves = 8192 waves = 2048 blocks of 4 waves
    dim3 grid(2048);
    dim3 block(256);
    avefilter_kernel<<<grid, block, 0, stream>>>(x, wgt, out);
}